// Round 18
// baseline (151.796 us; speedup 1.0000x reference)
//
#include <hip/hip_runtime.h>
#include <hip/hip_bf16.h>
#include <math.h>

#define N_RES 512
#define NPROJ 1152
#define LSTR  520

#define SC_QK 0.14433756729740643f   // sqrt(1/48)
#define SC_B  0.57735026918962576f   // sqrt(1/3)
#define SC_HW 0.13608276348795434f   // sqrt(1/54)

typedef __attribute__((ext_vector_type(8))) short short8;
typedef __attribute__((ext_vector_type(4))) float f32x4;

// hardware bf16 conversion (compiler emits v_cvt_pk_bf16_f32 pairs; m240)
static __device__ __forceinline__ short f2bf(float f) {
    return __builtin_bit_cast(short, __float2bfloat16(f));
}

// branchy weight/bias source selectors (block-uniform col ranges in k_proj)
static __device__ __forceinline__ float wsrc(
    const float* __restrict__ Wq,  const float* __restrict__ Wkv,
    const float* __restrict__ Wqp, const float* __restrict__ Wkvp,
    int k, int col)
{
    if (col < 192)      return Wq  [(size_t)k*192 + col];
    else if (col < 576) return Wkv [(size_t)k*384 + col-192];
    else if (col < 720) return Wqp [(size_t)k*144 + col-576];
    else                return Wkvp[(size_t)k*432 + col-720];
}
static __device__ __forceinline__ float bsrc(
    const float* __restrict__ bq,  const float* __restrict__ bkv,
    const float* __restrict__ bqp, const float* __restrict__ bkvp, int col)
{
    if (col < 192)      return bq  [col];
    else if (col < 576) return bkv [col-192];
    else if (col < 720) return bqp [col-576];
    else                return bkvp[col-720];
}

// ---------------------------------------------------------------------------
// k_proj: proj = s @ [Wq|Wkv|Wqp|Wkvp] + bias (+ kT4 packed transposed K).
// kT4 layout: [h][cq][j][4] = K[j][h][cq*4+e] -> b128 reads in k_logit.
// Block (0,0) prologue: wbt (WbT[12][128]) + softplus(head_w)*SC_HW.
// ---------------------------------------------------------------------------
__global__ __launch_bounds__(256) void k_proj(
    const float* __restrict__ s,
    const float* __restrict__ Wq,  const float* __restrict__ bq,
    const float* __restrict__ Wkv, const float* __restrict__ bkv,
    const float* __restrict__ Wqp, const float* __restrict__ bqp,
    const float* __restrict__ Wkvp,const float* __restrict__ bkvp,
    const float* __restrict__ Wb,  const float* __restrict__ head_w,
    float* __restrict__ proj, float* __restrict__ kT, float* __restrict__ wbt)
{
    __shared__ float A[32*36];
    __shared__ float Bt[32*36];
    const int t    = threadIdx.x;
    const int wave = t >> 6, lane = t & 63;
    const int wr   = wave >> 1, wc = wave & 1;
    const int ly   = lane >> 3, lx = lane & 7;
    const int i0 = blockIdx.x * 32, c0 = blockIdx.y * 32;
    const int sr = t >> 3, sk = (t & 7) * 4;

    if (blockIdx.x == 0 && blockIdx.y == 0) {   // prologue
        for (int idx = t; idx < 1536; idx += 256) {
            const int h = idx >> 7, c = idx & 127;
            wbt[idx] = Wb[c*12 + h];
        }
        if (t < 12)
            wbt[1536 + t] = log1pf(expf(head_w[t])) * SC_HW;
    }

    float acc00=0.f, acc01=0.f, acc10=0.f, acc11=0.f;
    for (int k0 = 0; k0 < 384; k0 += 32) {
        __syncthreads();
        *(float4*)&A[sr*36 + sk] = *(const float4*)&s[(size_t)(i0+sr)*384 + k0 + sk];
        const int col = c0 + sk;
        float4 wv;
        wv.x = wsrc(Wq,Wkv,Wqp,Wkvp, k0+sr, col+0);
        wv.y = wsrc(Wq,Wkv,Wqp,Wkvp, k0+sr, col+1);
        wv.z = wsrc(Wq,Wkv,Wqp,Wkvp, k0+sr, col+2);
        wv.w = wsrc(Wq,Wkv,Wqp,Wkvp, k0+sr, col+3);
        Bt[(sk+0)*36 + sr] = wv.x;
        Bt[(sk+1)*36 + sr] = wv.y;
        Bt[(sk+2)*36 + sr] = wv.z;
        Bt[(sk+3)*36 + sr] = wv.w;
        __syncthreads();
        #pragma unroll
        for (int k4 = 0; k4 < 32; k4 += 4) {
            const float4 a0 = *(const float4*)&A [(wr*16 + ly*2 + 0)*36 + k4];
            const float4 a1 = *(const float4*)&A [(wr*16 + ly*2 + 1)*36 + k4];
            const float4 b0 = *(const float4*)&Bt[(wc*16 + lx*2 + 0)*36 + k4];
            const float4 b1 = *(const float4*)&Bt[(wc*16 + lx*2 + 1)*36 + k4];
            acc00 = fmaf(a0.x,b0.x, fmaf(a0.y,b0.y, fmaf(a0.z,b0.z, fmaf(a0.w,b0.w, acc00))));
            acc01 = fmaf(a0.x,b1.x, fmaf(a0.y,b1.y, fmaf(a0.z,b1.z, fmaf(a0.w,b1.w, acc01))));
            acc10 = fmaf(a1.x,b0.x, fmaf(a1.y,b0.y, fmaf(a1.z,b0.z, fmaf(a1.w,b0.w, acc10))));
            acc11 = fmaf(a1.x,b1.x, fmaf(a1.y,b1.y, fmaf(a1.z,b1.z, fmaf(a1.w,b1.w, acc11))));
        }
    }
    #pragma unroll
    for (int r = 0; r < 2; ++r)
        #pragma unroll
        for (int c = 0; c < 2; ++c) {
            const int row = i0 + wr*16 + ly*2 + r;
            const int col = c0 + wc*16 + lx*2 + c;
            const float v = (r ? (c ? acc11 : acc10) : (c ? acc01 : acc00))
                            + bsrc(bq,bkv,bqp,bkvp, col);
            proj[(size_t)row*NPROJ + col] = v;
            if (col >= 192 && col < 576) {
                const int w = (col - 192) & 31;
                if (w < 16) {
                    const int h = (col - 192) >> 5;
                    kT[((size_t)(h*4 + (w >> 2))*512 + row)*4 + (w & 3)] = v;
                }
            }
        }
}

// ---------------------------------------------------------------------------
// k_rot: rotate/translate qp & kvp. kp packed: kpT[h][eq][i][4].
// ---------------------------------------------------------------------------
__global__ __launch_bounds__(192) void k_rot(
    const float* __restrict__ proj, const float* __restrict__ rots,
    const float* __restrict__ trans,
    float* __restrict__ qp_g, float* __restrict__ kpT, float* __restrict__ vp_g)
{
    const int i = blockIdx.x;
    const int t = threadIdx.x;
    const float* R = rots  + (size_t)i * 9;
    const float* T = trans + (size_t)i * 3;
    const float* row = proj + (size_t)i * NPROJ;
    const float r00=R[0],r01=R[1],r02=R[2],r10=R[3],r11=R[4],r12=R[5],r20=R[6],r21=R[7],r22=R[8];
    const float t0=T[0], t1=T[1], t2=T[2];
    if (t < 48) {
        const int p = t;
        const float v0 = row[576 + p], v1 = row[576 + 48 + p], v2 = row[576 + 96 + p];
        float* dst = qp_g + (size_t)i*144 + p*3;
        dst[0] = r00*v0 + r01*v1 + r02*v2 + t0;
        dst[1] = r10*v0 + r11*v1 + r12*v2 + t1;
        dst[2] = r20*v0 + r21*v1 + r22*v2 + t2;
    } else {
        const int p = t - 48;
        const float v0 = row[720 + p], v1 = row[720 + 144 + p], v2 = row[720 + 288 + p];
        const float o0 = r00*v0 + r01*v1 + r02*v2 + t0;
        const float o1 = r10*v0 + r11*v1 + r12*v2 + t1;
        const float o2 = r20*v0 + r21*v1 + r22*v2 + t2;
        const int h = p / 12, pp = p % 12;
        if (pp < 4) {
            const int d0 = pp*3;
            kpT[((size_t)(h*3 + ((d0+0)>>2))*512 + i)*4 + ((d0+0)&3)] = o0;
            kpT[((size_t)(h*3 + ((d0+1)>>2))*512 + i)*4 + ((d0+1)&3)] = o1;
            kpT[((size_t)(h*3 + ((d0+2)>>2))*512 + i)*4 + ((d0+2)&3)] = o2;
        } else {
            float* dst = vp_g + (size_t)i*288 + (h*8+(pp-4))*3;
            dst[0]=o0; dst[1]=o1; dst[2]=o2;
        }
    }
}

// ---------------------------------------------------------------------------
// k_logit: bias via MFMA tile + qk + point + mask -> raw logits.
// grid (512 i, 8 jq) x 256 thr.  __launch_bounds__(256, 8): cap regalloc at
// 64 (incl. 4 MFMA AGPRs on the unified file) -> 8 waves/SIMD residency.
// ---------------------------------------------------------------------------
__global__ __launch_bounds__(256, 8) void k_logit(
    const float* __restrict__ proj, const float* __restrict__ z,
    const float* __restrict__ mask,
    const float* __restrict__ wbt,  const float* __restrict__ bb,
    const float* __restrict__ qp_g, const float* __restrict__ kT,
    const float* __restrict__ kpT,
    float* __restrict__ a)
{
    const int i  = blockIdx.x, jq = blockIdx.y;   // jq 0..7
    const int t  = threadIdx.x;
    const int j0 = jq * 64;

    __shared__ float qlds[336];       // [0,192)=q, [192,336)=qp
    __shared__ float biasr[64 * 13];  // [row][h], pad 13

    for (int idx = t; idx < 336; idx += 256)
        qlds[idx] = (idx < 192) ? proj[(size_t)i*NPROJ + idx]
                                : qp_g[(size_t)i*144 + (idx-192)];

    // ---- phase 1: bias = z @ Wb via one 16-row MFMA tile per wave ----
    const int wv = t >> 6, lane = t & 63;
    const int r16 = lane & 15, g = lane >> 4;

    short8 bf[4];
    #pragma unroll
    for (int ck = 0; ck < 4; ++ck) {
        float w[8];
        if (r16 < 12) {
            const float4 w0 = *(const float4*)&wbt[r16*128 + ck*32 + g*8];
            const float4 w1 = *(const float4*)&wbt[r16*128 + ck*32 + g*8 + 4];
            w[0]=w0.x; w[1]=w0.y; w[2]=w0.z; w[3]=w0.w;
            w[4]=w1.x; w[5]=w1.y; w[6]=w1.z; w[7]=w1.w;
        } else {
            #pragma unroll
            for (int e = 0; e < 8; ++e) w[e] = 0.f;
        }
        #pragma unroll
        for (int e = 0; e < 8; ++e) bf[ck][e] = f2bf(w[e]);
    }

    const float* zrow = z + ((size_t)i*N_RES + j0 + wv*16 + r16)*128 + g*8;
    f32x4 bacc = {0.f, 0.f, 0.f, 0.f};
    #pragma unroll
    for (int ck = 0; ck < 4; ++ck) {
        const float4 z0 = *(const float4*)&zrow[ck*32];
        const float4 z1 = *(const float4*)&zrow[ck*32 + 4];
        short8 af;
        af[0]=f2bf(z0.x); af[1]=f2bf(z0.y); af[2]=f2bf(z0.z); af[3]=f2bf(z0.w);
        af[4]=f2bf(z1.x); af[5]=f2bf(z1.y); af[6]=f2bf(z1.z); af[7]=f2bf(z1.w);
        bacc = __builtin_amdgcn_mfma_f32_16x16x32_bf16(af, bf[ck], bacc, 0, 0, 0);
    }
    if (r16 < 12) {   // C: col h = r16, local row = wv*16 + g*4 + r
        const int jl = wv*16 + g*4;
        biasr[(jl+0)*13 + r16] = bacc[0];
        biasr[(jl+1)*13 + r16] = bacc[1];
        biasr[(jl+2)*13 + r16] = bacc[2];
        biasr[(jl+3)*13 + r16] = bacc[3];
    }
    __syncthreads();

    // ---- phase 3: logits via packed kT4/kpT4 (b128, coalesced along j) ----
    const int j = t & 63, gj = j0 + j;
    const int hgrp = t >> 6;              // heads hgrp*3..hgrp*3+2
    const float mterm = 100000.0f * (mask[i]*mask[gj] - 1.0f);
    #pragma unroll
    for (int u = 0; u < 3; ++u) {
        const int h = hgrp*3 + u;
        const float hw = wbt[1536 + h];   // precomputed softplus*SC_HW (s_load)
        float qk = 0.f;
        #pragma unroll
        for (int cq = 0; cq < 4; ++cq) {
            const float4 k4 = *(const float4*)&kT[((size_t)(h*4+cq)*512 + gj)*4];
            qk = fmaf(qlds[h*16+cq*4+0], k4.x,
                 fmaf(qlds[h*16+cq*4+1], k4.y,
                 fmaf(qlds[h*16+cq*4+2], k4.z,
                 fmaf(qlds[h*16+cq*4+3], k4.w, qk))));
        }
        float s2 = 0.f;
        #pragma unroll
        for (int eq = 0; eq < 3; ++eq) {
            const float4 kp4 = *(const float4*)&kpT[((size_t)(h*3+eq)*512 + gj)*4];
            const float d0 = qlds[192 + h*12 + eq*4+0] - kp4.x;
            const float d1 = qlds[192 + h*12 + eq*4+1] - kp4.y;
            const float d2 = qlds[192 + h*12 + eq*4+2] - kp4.z;
            const float d3 = qlds[192 + h*12 + eq*4+3] - kp4.w;
            s2 = fmaf(d0,d0, fmaf(d1,d1, fmaf(d2,d2, fmaf(d3,d3, s2))));
        }
        a[(size_t)i*6144 + h*512 + gj] =
            fmaf(qk, SC_QK,
            fmaf(biasr[j*13+h] + bb[h], SC_B,
            fmaf(-0.5f*hw, s2, mterm)));
    }
}

// ---------------------------------------------------------------------------
// k_avp: fused softmax + o/o_pt + o_pair (r15-best o_pair form).
// Block = residue i, 512 thr.
// ---------------------------------------------------------------------------
__global__ __launch_bounds__(512) void k_avp(
    const float* __restrict__ a, const float* __restrict__ proj,
    const float* __restrict__ vp_g, const float* __restrict__ z,
    const float* __restrict__ rots, const float* __restrict__ trans,
    float* __restrict__ cat)
{
    const int i = blockIdx.x;
    const int t = threadIdx.x;
    __shared__ float al[12*LSTR];        // 24.96 KB
    __shared__ float opt_raw[288];
    __shared__ float plds[4*12*128];     // 24 KB o_pair partials

    #pragma unroll
    for (int p = 0; p < 3; ++p) {
        const int el = (p*512 + t) * 4;
        const int h = el >> 9, jj = el & 511;
        *(float4*)&al[h*LSTR + jj] = *(const float4*)&a[(size_t)i*6144 + el];
    }
    __syncthreads();

    // ---- softmax in LDS: wave wv handles rows wv, wv+8 ----
    const int wv = t >> 6, lane = t & 63;
    for (int row = wv; row < 12; row += 8) {
        float e[8];
        float m = -3.4e38f;
        #pragma unroll
        for (int u = 0; u < 8; ++u) { e[u] = al[row*LSTR + lane + u*64]; m = fmaxf(m, e[u]); }
        #pragma unroll
        for (int d = 1; d < 64; d <<= 1) m = fmaxf(m, __shfl_xor(m, d, 64));
        float ssum = 0.f;
        #pragma unroll
        for (int u = 0; u < 8; ++u) { e[u] = expf(e[u] - m); ssum += e[u]; }
        #pragma unroll
        for (int d = 1; d < 64; d <<= 1) ssum += __shfl_xor(ssum, d, 64);
        const float inv = 1.f / ssum;
        #pragma unroll
        for (int u = 0; u < 8; ++u) al[row*LSTR + lane + u*64] = e[u] * inv;
    }
    __syncthreads();

    // ---- o / o_pt phase ----
    float acc0 = 0.f;
    if (t < 480) {
        const int hh    = (t < 192) ? (t >> 4) : (t - 192) / 24;
        const int o_off = 192 + (t >> 4)*32 + 16 + (t & 15);
        const int vi    = t - 192;
        const float* al0 = al + hh*LSTR;
        for (int j0 = 0; j0 < N_RES; j0 += 8) {
            const float4 a00 = *(const float4*)&al0[j0];
            const float4 a01 = *(const float4*)&al0[j0+4];
            float v[8];
            if (t < 192) {
                #pragma unroll
                for (int w = 0; w < 8; ++w) v[w] = proj[(size_t)(j0+w)*NPROJ + o_off];
            } else {
                #pragma unroll
                for (int w = 0; w < 8; ++w) v[w] = vp_g[(size_t)(j0+w)*288 + vi];
            }
            acc0 = fmaf(a00.x,v[0], fmaf(a00.y,v[1], fmaf(a00.z,v[2], fmaf(a00.w,v[3], acc0))));
            acc0 = fmaf(a01.x,v[4], fmaf(a01.y,v[5], fmaf(a01.z,v[6], fmaf(a01.w,v[7], acc0))));
        }
        if (t < 192) cat[(size_t)i*2112 + t] = acc0;
        else         opt_raw[t - 192] = acc0;
    }

    // ---- o_pair phase: c = t&127, j-quarter = t>>7, all 12 heads ----
    {
        const int c = t & 127, jq = t >> 7;
        const float* zb = z + (size_t)i*65536 + (size_t)jq*128*128 + c;
        float accp[12] = {0,0,0,0,0,0,0,0,0,0,0,0};
        for (int j4 = 0; j4 < 128; j4 += 4) {
            const float z0 = zb[(size_t)(j4+0)*128];
            const float z1 = zb[(size_t)(j4+1)*128];
            const float z2 = zb[(size_t)(j4+2)*128];
            const float z3 = zb[(size_t)(j4+3)*128];
            #pragma unroll
            for (int h = 0; h < 12; ++h) {
                const float4 a4 = *(const float4*)&al[h*LSTR + jq*128 + j4];
                accp[h] = fmaf(a4.x, z0, fmaf(a4.y, z1,
                          fmaf(a4.z, z2, fmaf(a4.w, z3, accp[h]))));
            }
        }
        #pragma unroll
        for (int h = 0; h < 12; ++h)
            plds[(jq*12 + h)*128 + c] = accp[h];
    }
    __syncthreads();

    float* crow = cat + (size_t)i * 2112;
    // o_pair reduce: 1536 outputs, 3 per thread
    #pragma unroll
    for (int e = 0; e < 3; ++e) {
        const int o = t + e*512;
        const int h = o >> 7, c = o & 127;
        const float sum = plds[(0*12+h)*128 + c] + plds[(1*12+h)*128 + c]
                        + plds[(2*12+h)*128 + c] + plds[(3*12+h)*128 + c];
        crow[576 + h*128 + c] = sum;
    }
    // o_pt inverse transform + norm
    if (t < 96) {   // t = h*8+p
        const float* R = rots  + (size_t)i * 9;
        const float* T = trans + (size_t)i * 3;
        const float r0 = opt_raw[t*3+0] - T[0];
        const float r1 = opt_raw[t*3+1] - T[1];
        const float r2 = opt_raw[t*3+2] - T[2];
        const float o0 = R[0]*r0 + R[3]*r1 + R[6]*r2;
        const float o1 = R[1]*r0 + R[4]*r1 + R[7]*r2;
        const float o2 = R[2]*r0 + R[5]*r1 + R[8]*r2;
        crow[192 +   0 + t] = o0;
        crow[192 +  96 + t] = o1;
        crow[192 + 192 + t] = o2;
        crow[480 + t] = sqrtf(o0*o0 + o1*o1 + o2*o2 + 1e-8f);
    }
}

// ---------------------------------------------------------------------------
// k_outp: split-K partials of cat @ Wout (K=2112=6x352). 256 thr, 2x2 waves.
// ---------------------------------------------------------------------------
__global__ __launch_bounds__(256) void k_outp(
    const float* __restrict__ cat, const float* __restrict__ Wout,
    float* __restrict__ outp)
{
    __shared__ float A[32*36];
    __shared__ float Bt[32*36];
    const int t    = threadIdx.x;
    const int wave = t >> 6, lane = t & 63;
    const int wr   = wave >> 1, wc = wave & 1;
    const int ly   = lane >> 3, lx = lane & 7;
    const int i0 = blockIdx.x * 32, n0 = blockIdx.y * 32;
    const int kq = blockIdx.z;
    const int sr = t >> 3, sk = (t & 7) * 4;

    float acc00=0.f, acc01=0.f, acc10=0.f, acc11=0.f;
    for (int kc = 0; kc < 11; ++kc) {
        const int kb = kq*352 + kc*32;
        __syncthreads();
        *(float4*)&A[sr*36 + sk] = *(const float4*)&cat[(size_t)(i0+sr)*2112 + kb + sk];
        const float4 wv = *(const float4*)&Wout[(size_t)(kb+sr)*384 + n0 + sk];
        Bt[(sk+0)*36 + sr] = wv.x;
        Bt[(sk+1)*36 + sr] = wv.y;
        Bt[(sk+2)*36 + sr] = wv.z;
        Bt[(sk+3)*36 + sr] = wv.w;
        __syncthreads();
        #pragma unroll
        for (int k4 = 0; k4 < 32; k4 += 4) {
            const float4 a0 = *(const float4*)&A [(wr*16 + ly*2 + 0)*36 + k4];
            const float4 a1 = *(const float4*)&A [(wr*16 + ly*2 + 1)*36 + k4];
            const float4 b0 = *(const float4*)&Bt[(wc*16 + lx*2 + 0)*36 + k4];
            const float4 b1 = *(const float4*)&Bt[(wc*16 + lx*2 + 1)*36 + k4];
            acc00 = fmaf(a0.x,b0.x, fmaf(a0.y,b0.y, fmaf(a0.z,b0.z, fmaf(a0.w,b0.w, acc00))));
            acc01 = fmaf(a0.x,b1.x, fmaf(a0.y,b1.y, fmaf(a0.z,b1.z, fmaf(a0.w,b1.w, acc01))));
            acc10 = fmaf(a1.x,b0.x, fmaf(a1.y,b0.y, fmaf(a1.z,b0.z, fmaf(a1.w,b0.w, acc10))));
            acc11 = fmaf(a1.x,b1.x, fmaf(a1.y,b1.y, fmaf(a1.z,b1.z, fmaf(a1.w,b1.w, acc11))));
        }
    }
    float* op = outp + (size_t)kq * 196608;
    const int row = i0 + wr*16 + ly*2, col = n0 + wc*16 + lx*2;
    op[(size_t)(row+0)*384 + col+0] = acc00;
    op[(size_t)(row+0)*384 + col+1] = acc01;
    op[(size_t)(row+1)*384 + col+0] = acc10;
    op[(size_t)(row+1)*384 + col+1] = acc11;
}

__global__ __launch_bounds__(256) void k_red(
    const float* __restrict__ outp, const float* __restrict__ bout,
    float* __restrict__ out)
{
    const int e = blockIdx.x * 256 + threadIdx.x;
    float v = bout[e % 384];
    #pragma unroll
    for (int q = 0; q < 6; ++q) v += outp[(size_t)q*196608 + e];
    out[e] = v;
}

// ---------------------------------------------------------------------------
extern "C" void kernel_launch(void* const* d_in, const int* in_sizes, int n_in,
                              void* d_out, int out_size, void* d_ws, size_t ws_size,
                              hipStream_t stream)
{
    const float* s      = (const float*)d_in[0];
    const float* z      = (const float*)d_in[1];
    const float* rots   = (const float*)d_in[2];
    const float* trans  = (const float*)d_in[3];
    const float* mask   = (const float*)d_in[4];
    const float* Wq     = (const float*)d_in[5];
    const float* bq     = (const float*)d_in[6];
    const float* Wkv    = (const float*)d_in[7];
    const float* bkv    = (const float*)d_in[8];
    const float* Wqp    = (const float*)d_in[9];
    const float* bqp    = (const float*)d_in[10];
    const float* Wkvp   = (const float*)d_in[11];
    const float* bkvp   = (const float*)d_in[12];
    const float* Wb     = (const float*)d_in[13];
    const float* bb     = (const float*)d_in[14];
    const float* head_w = (const float*)d_in[15];
    const float* Wout   = (const float*)d_in[16];
    const float* bout   = (const float*)d_in[17];
    float* out = (float*)d_out;

    float* ws    = (float*)d_ws;
    float* proj  = ws;                      // 589824
    float* qp_g  = proj  + 589824;          // 73728
    float* kpT   = qp_g  + 73728;           // 73728  [h][eq][512][4]
    float* vp_g  = kpT   + 73728;           // 147456
    float* kT    = vp_g  + 147456;          // 98304  [h][cq][512][4]
    float* abuf  = kT    + 98304;           // 3145728 (raw logits; later outp)
    float* cat   = abuf  + 3145728;         // 1081344
    float* wbt   = cat   + 1081344;         // 1548  WbT[12][128] + hw[12]
    float* outp  = abuf;                    // 1179648 <= 3145728

    k_proj <<<dim3(16, 36), 256, 0, stream>>>(s, Wq, bq, Wkv, bkv, Wqp, bqp,
                                              Wkvp, bkvp, Wb, head_w,
                                              proj, kT, wbt);
    k_rot  <<<512, 192, 0, stream>>>(proj, rots, trans, qp_g, kpT, vp_g);
    k_logit<<<dim3(512, 8), 256, 0, stream>>>(proj, z, mask, wbt, bb,
                                              qp_g, kT, kpT, abuf);
    k_avp  <<<512, 512, 0, stream>>>(abuf, proj, vp_g, z, rots, trans, cat);
    k_outp <<<dim3(16, 12, 6), 256, 0, stream>>>(cat, Wout, outp);
    k_red  <<<768, 256, 0, stream>>>(outp, bout, out);
}

// Round 19
// 144.014 us; speedup vs baseline: 1.0540x; 1.0540x over previous
//
#include <hip/hip_runtime.h>
#include <hip/hip_bf16.h>
#include <math.h>

#define N_RES 512
#define NPROJ 1152
#define LSTR  520

#define SC_QK 0.14433756729740643f   // sqrt(1/48)
#define SC_B  0.57735026918962576f   // sqrt(1/3)
#define SC_HW 0.13608276348795434f   // sqrt(1/54)

typedef __attribute__((ext_vector_type(8))) short short8;
typedef __attribute__((ext_vector_type(4))) float f32x4;

// hardware bf16 conversion (compiler emits v_cvt_pk_bf16_f32 pairs; m240)
static __device__ __forceinline__ short f2bf(float f) {
    return __builtin_bit_cast(short, __float2bfloat16(f));
}

// branchy weight/bias source selectors (block-uniform col ranges in k_proj)
static __device__ __forceinline__ float wsrc(
    const float* __restrict__ Wq,  const float* __restrict__ Wkv,
    const float* __restrict__ Wqp, const float* __restrict__ Wkvp,
    int k, int col)
{
    if (col < 192)      return Wq  [(size_t)k*192 + col];
    else if (col < 576) return Wkv [(size_t)k*384 + col-192];
    else if (col < 720) return Wqp [(size_t)k*144 + col-576];
    else                return Wkvp[(size_t)k*432 + col-720];
}
static __device__ __forceinline__ float bsrc(
    const float* __restrict__ bq,  const float* __restrict__ bkv,
    const float* __restrict__ bqp, const float* __restrict__ bkvp, int col)
{
    if (col < 192)      return bq  [col];
    else if (col < 576) return bkv [col-192];
    else if (col < 720) return bqp [col-576];
    else                return bkvp[col-720];
}

// ---------------------------------------------------------------------------
// k_proj: proj = s @ [Wq|Wkv|Wqp|Wkvp] + bias (+ kT transposed K copy).
// 256 thr, 2x2 wave grid, 2x2 reg tile. Block (0,0) prologue: wbt (WbT) +
// precomputed per-head softplus weights at wbt[1536..1547].
// ---------------------------------------------------------------------------
__global__ __launch_bounds__(256) void k_proj(
    const float* __restrict__ s,
    const float* __restrict__ Wq,  const float* __restrict__ bq,
    const float* __restrict__ Wkv, const float* __restrict__ bkv,
    const float* __restrict__ Wqp, const float* __restrict__ bqp,
    const float* __restrict__ Wkvp,const float* __restrict__ bkvp,
    const float* __restrict__ Wb,  const float* __restrict__ head_w,
    float* __restrict__ proj, float* __restrict__ kT, float* __restrict__ wbt)
{
    __shared__ float A[32*36];
    __shared__ float Bt[32*36];
    const int t    = threadIdx.x;
    const int wave = t >> 6, lane = t & 63;
    const int wr   = wave >> 1, wc = wave & 1;
    const int ly   = lane >> 3, lx = lane & 7;
    const int i0 = blockIdx.x * 32, c0 = blockIdx.y * 32;
    const int sr = t >> 3, sk = (t & 7) * 4;

    if (blockIdx.x == 0 && blockIdx.y == 0) {   // prologue
        for (int idx = t; idx < 1536; idx += 256) {
            const int h = idx >> 7, c = idx & 127;
            wbt[idx] = Wb[c*12 + h];
        }
        if (t < 12)
            wbt[1536 + t] = log1pf(expf(head_w[t])) * SC_HW;
    }

    float acc00=0.f, acc01=0.f, acc10=0.f, acc11=0.f;
    for (int k0 = 0; k0 < 384; k0 += 32) {
        __syncthreads();
        *(float4*)&A[sr*36 + sk] = *(const float4*)&s[(size_t)(i0+sr)*384 + k0 + sk];
        const int col = c0 + sk;
        float4 wv;
        wv.x = wsrc(Wq,Wkv,Wqp,Wkvp, k0+sr, col+0);
        wv.y = wsrc(Wq,Wkv,Wqp,Wkvp, k0+sr, col+1);
        wv.z = wsrc(Wq,Wkv,Wqp,Wkvp, k0+sr, col+2);
        wv.w = wsrc(Wq,Wkv,Wqp,Wkvp, k0+sr, col+3);
        Bt[(sk+0)*36 + sr] = wv.x;
        Bt[(sk+1)*36 + sr] = wv.y;
        Bt[(sk+2)*36 + sr] = wv.z;
        Bt[(sk+3)*36 + sr] = wv.w;
        __syncthreads();
        #pragma unroll
        for (int k4 = 0; k4 < 32; k4 += 4) {
            const float4 a0 = *(const float4*)&A [(wr*16 + ly*2 + 0)*36 + k4];
            const float4 a1 = *(const float4*)&A [(wr*16 + ly*2 + 1)*36 + k4];
            const float4 b0 = *(const float4*)&Bt[(wc*16 + lx*2 + 0)*36 + k4];
            const float4 b1 = *(const float4*)&Bt[(wc*16 + lx*2 + 1)*36 + k4];
            acc00 = fmaf(a0.x,b0.x, fmaf(a0.y,b0.y, fmaf(a0.z,b0.z, fmaf(a0.w,b0.w, acc00))));
            acc01 = fmaf(a0.x,b1.x, fmaf(a0.y,b1.y, fmaf(a0.z,b1.z, fmaf(a0.w,b1.w, acc01))));
            acc10 = fmaf(a1.x,b0.x, fmaf(a1.y,b0.y, fmaf(a1.z,b0.z, fmaf(a1.w,b0.w, acc10))));
            acc11 = fmaf(a1.x,b1.x, fmaf(a1.y,b1.y, fmaf(a1.z,b1.z, fmaf(a1.w,b1.w, acc11))));
        }
    }
    #pragma unroll
    for (int r = 0; r < 2; ++r)
        #pragma unroll
        for (int c = 0; c < 2; ++c) {
            const int row = i0 + wr*16 + ly*2 + r;
            const int col = c0 + wc*16 + lx*2 + c;
            const float v = (r ? (c ? acc11 : acc10) : (c ? acc01 : acc00))
                            + bsrc(bq,bkv,bqp,bkvp, col);
            proj[(size_t)row*NPROJ + col] = v;
            if (col >= 192 && col < 576) {
                const int w = (col - 192) & 31;
                if (w < 16)
                    kT[(size_t)((((col-192) >> 5) << 4) + w)*512 + row] = v;
            }
        }
}

// ---------------------------------------------------------------------------
// k_rot: rotate/translate qp & kvp. kp written TRANSPOSED: kpT[h*12+e][i].
// ---------------------------------------------------------------------------
__global__ __launch_bounds__(192) void k_rot(
    const float* __restrict__ proj, const float* __restrict__ rots,
    const float* __restrict__ trans,
    float* __restrict__ qp_g, float* __restrict__ kpT, float* __restrict__ vp_g)
{
    const int i = blockIdx.x;
    const int t = threadIdx.x;
    const float* R = rots  + (size_t)i * 9;
    const float* T = trans + (size_t)i * 3;
    const float* row = proj + (size_t)i * NPROJ;
    const float r00=R[0],r01=R[1],r02=R[2],r10=R[3],r11=R[4],r12=R[5],r20=R[6],r21=R[7],r22=R[8];
    const float t0=T[0], t1=T[1], t2=T[2];
    if (t < 48) {
        const int p = t;
        const float v0 = row[576 + p], v1 = row[576 + 48 + p], v2 = row[576 + 96 + p];
        float* dst = qp_g + (size_t)i*144 + p*3;
        dst[0] = r00*v0 + r01*v1 + r02*v2 + t0;
        dst[1] = r10*v0 + r11*v1 + r12*v2 + t1;
        dst[2] = r20*v0 + r21*v1 + r22*v2 + t2;
    } else {
        const int p = t - 48;
        const float v0 = row[720 + p], v1 = row[720 + 144 + p], v2 = row[720 + 288 + p];
        const float o0 = r00*v0 + r01*v1 + r02*v2 + t0;
        const float o1 = r10*v0 + r11*v1 + r12*v2 + t1;
        const float o2 = r20*v0 + r21*v1 + r22*v2 + t2;
        const int h = p / 12, pp = p % 12;
        if (pp < 4) {
            const int e = (h*4 + pp)*3;
            kpT[(size_t)(e+0)*512 + i] = o0;
            kpT[(size_t)(e+1)*512 + i] = o1;
            kpT[(size_t)(e+2)*512 + i] = o2;
        } else {
            float* dst = vp_g + (size_t)i*288 + (h*8+(pp-4))*3;
            dst[0]=o0; dst[1]=o1; dst[2]=o2;
        }
    }
}

// ---------------------------------------------------------------------------
// k_logit: bias via MFMA tile + qk + point + mask -> raw logits.
// grid (512 i, 8 jq) x 256 thr; wave wv owns rows [jq*64 + wv*16, +16).
// ---------------------------------------------------------------------------
__global__ __launch_bounds__(256, 4) void k_logit(
    const float* __restrict__ proj, const float* __restrict__ z,
    const float* __restrict__ mask,
    const float* __restrict__ wbt,  const float* __restrict__ bb,
    const float* __restrict__ qp_g, const float* __restrict__ kT,
    const float* __restrict__ kpT,
    float* __restrict__ a)
{
    const int i  = blockIdx.x, jq = blockIdx.y;   // jq 0..7
    const int t  = threadIdx.x;
    const int j0 = jq * 64;

    __shared__ float qlds[336];       // [0,192)=q, [192,336)=qp
    __shared__ float biasr[64 * 13];  // [row][h], pad 13

    for (int idx = t; idx < 336; idx += 256)
        qlds[idx] = (idx < 192) ? proj[(size_t)i*NPROJ + idx]
                                : qp_g[(size_t)i*144 + (idx-192)];

    // ---- phase 1: bias = z @ Wb via one 16-row MFMA tile per wave ----
    const int wv = t >> 6, lane = t & 63;
    const int r16 = lane & 15, g = lane >> 4;

    short8 bf[4];
    #pragma unroll
    for (int ck = 0; ck < 4; ++ck) {
        float w[8];
        if (r16 < 12) {
            const float4 w0 = *(const float4*)&wbt[r16*128 + ck*32 + g*8];
            const float4 w1 = *(const float4*)&wbt[r16*128 + ck*32 + g*8 + 4];
            w[0]=w0.x; w[1]=w0.y; w[2]=w0.z; w[3]=w0.w;
            w[4]=w1.x; w[5]=w1.y; w[6]=w1.z; w[7]=w1.w;
        } else {
            #pragma unroll
            for (int e = 0; e < 8; ++e) w[e] = 0.f;
        }
        #pragma unroll
        for (int e = 0; e < 8; ++e) bf[ck][e] = f2bf(w[e]);
    }

    const float* zrow = z + ((size_t)i*N_RES + j0 + wv*16 + r16)*128 + g*8;
    f32x4 bacc = {0.f, 0.f, 0.f, 0.f};
    #pragma unroll
    for (int ck = 0; ck < 4; ++ck) {
        const float4 z0 = *(const float4*)&zrow[ck*32];
        const float4 z1 = *(const float4*)&zrow[ck*32 + 4];
        short8 af;
        af[0]=f2bf(z0.x); af[1]=f2bf(z0.y); af[2]=f2bf(z0.z); af[3]=f2bf(z0.w);
        af[4]=f2bf(z1.x); af[5]=f2bf(z1.y); af[6]=f2bf(z1.z); af[7]=f2bf(z1.w);
        bacc = __builtin_amdgcn_mfma_f32_16x16x32_bf16(af, bf[ck], bacc, 0, 0, 0);
    }
    if (r16 < 12) {   // C: col h = r16, local row = wv*16 + g*4 + r
        const int jl = wv*16 + g*4;
        biasr[(jl+0)*13 + r16] = bacc[0];
        biasr[(jl+1)*13 + r16] = bacc[1];
        biasr[(jl+2)*13 + r16] = bacc[2];
        biasr[(jl+3)*13 + r16] = bacc[3];
    }
    __syncthreads();

    // ---- phase 3: logits via kT/kpT (coalesced along j) ----
    const int j = t & 63, gj = j0 + j;
    const int hgrp = t >> 6;              // heads hgrp*3..hgrp*3+2
    const float mterm = 100000.0f * (mask[i]*mask[gj] - 1.0f);
    #pragma unroll
    for (int u = 0; u < 3; ++u) {
        const int h = hgrp*3 + u;
        const float hw = wbt[1536 + h];   // precomputed softplus*SC_HW (s_load)
        float qk = 0.f;
        #pragma unroll
        for (int c = 0; c < 16; ++c)
            qk = fmaf(qlds[h*16+c], kT[(size_t)(h*16+c)*512 + gj], qk);
        float s2 = 0.f;
        #pragma unroll
        for (int e = 0; e < 12; ++e) {
            const float d = qlds[192 + h*12 + e] - kpT[(size_t)(h*12+e)*512 + gj];
            s2 = fmaf(d, d, s2);
        }
        a[(size_t)i*6144 + h*512 + gj] =
            fmaf(qk, SC_QK,
            fmaf(biasr[j*13+h] + bb[h], SC_B,
            fmaf(-0.5f*hw, s2, mterm)));
    }
}

// ---------------------------------------------------------------------------
// k_avp: fused softmax + o/o_pt + o_pair. Block = residue i, 512 thr.
// ---------------------------------------------------------------------------
__global__ __launch_bounds__(512) void k_avp(
    const float* __restrict__ a, const float* __restrict__ proj,
    const float* __restrict__ vp_g, const float* __restrict__ z,
    const float* __restrict__ rots, const float* __restrict__ trans,
    float* __restrict__ cat)
{
    const int i = blockIdx.x;
    const int t = threadIdx.x;
    __shared__ float al[12*LSTR];        // 24.96 KB
    __shared__ float opt_raw[288];
    __shared__ float plds[4*12*128];     // 24 KB o_pair partials

    #pragma unroll
    for (int p = 0; p < 3; ++p) {
        const int el = (p*512 + t) * 4;
        const int h = el >> 9, jj = el & 511;
        *(float4*)&al[h*LSTR + jj] = *(const float4*)&a[(size_t)i*6144 + el];
    }
    __syncthreads();

    // ---- softmax in LDS: wave wv handles rows wv, wv+8 ----
    const int wv = t >> 6, lane = t & 63;
    for (int row = wv; row < 12; row += 8) {
        float e[8];
        float m = -3.4e38f;
        #pragma unroll
        for (int u = 0; u < 8; ++u) { e[u] = al[row*LSTR + lane + u*64]; m = fmaxf(m, e[u]); }
        #pragma unroll
        for (int d = 1; d < 64; d <<= 1) m = fmaxf(m, __shfl_xor(m, d, 64));
        float ssum = 0.f;
        #pragma unroll
        for (int u = 0; u < 8; ++u) { e[u] = expf(e[u] - m); ssum += e[u]; }
        #pragma unroll
        for (int d = 1; d < 64; d <<= 1) ssum += __shfl_xor(ssum, d, 64);
        const float inv = 1.f / ssum;
        #pragma unroll
        for (int u = 0; u < 8; ++u) al[row*LSTR + lane + u*64] = e[u] * inv;
    }
    __syncthreads();

    // ---- o / o_pt phase ----
    float acc0 = 0.f;
    if (t < 480) {
        const int hh    = (t < 192) ? (t >> 4) : (t - 192) / 24;
        const int o_off = 192 + (t >> 4)*32 + 16 + (t & 15);
        const int vi    = t - 192;
        const float* al0 = al + hh*LSTR;
        for (int j0 = 0; j0 < N_RES; j0 += 8) {
            const float4 a00 = *(const float4*)&al0[j0];
            const float4 a01 = *(const float4*)&al0[j0+4];
            float v[8];
            if (t < 192) {
                #pragma unroll
                for (int w = 0; w < 8; ++w) v[w] = proj[(size_t)(j0+w)*NPROJ + o_off];
            } else {
                #pragma unroll
                for (int w = 0; w < 8; ++w) v[w] = vp_g[(size_t)(j0+w)*288 + vi];
            }
            acc0 = fmaf(a00.x,v[0], fmaf(a00.y,v[1], fmaf(a00.z,v[2], fmaf(a00.w,v[3], acc0))));
            acc0 = fmaf(a01.x,v[4], fmaf(a01.y,v[5], fmaf(a01.z,v[6], fmaf(a01.w,v[7], acc0))));
        }
        if (t < 192) cat[(size_t)i*2112 + t] = acc0;
        else         opt_raw[t - 192] = acc0;
    }

    // ---- o_pair phase: c = t&127, j-quarter = t>>7, all 12 heads ----
    {
        const int c = t & 127, jq = t >> 7;
        const float* zb = z + (size_t)i*65536 + (size_t)jq*128*128 + c;
        float accp[12] = {0,0,0,0,0,0,0,0,0,0,0,0};
        for (int j4 = 0; j4 < 128; j4 += 4) {
            const float z0 = zb[(size_t)(j4+0)*128];
            const float z1 = zb[(size_t)(j4+1)*128];
            const float z2 = zb[(size_t)(j4+2)*128];
            const float z3 = zb[(size_t)(j4+3)*128];
            #pragma unroll
            for (int h = 0; h < 12; ++h) {
                const float4 a4 = *(const float4*)&al[h*LSTR + jq*128 + j4];
                accp[h] = fmaf(a4.x, z0, fmaf(a4.y, z1,
                          fmaf(a4.z, z2, fmaf(a4.w, z3, accp[h]))));
            }
        }
        #pragma unroll
        for (int h = 0; h < 12; ++h)
            plds[(jq*12 + h)*128 + c] = accp[h];
    }
    __syncthreads();

    float* crow = cat + (size_t)i * 2112;
    // o_pair reduce: 1536 outputs, 3 per thread
    #pragma unroll
    for (int e = 0; e < 3; ++e) {
        const int o = t + e*512;
        const int h = o >> 7, c = o & 127;
        const float sum = plds[(0*12+h)*128 + c] + plds[(1*12+h)*128 + c]
                        + plds[(2*12+h)*128 + c] + plds[(3*12+h)*128 + c];
        crow[576 + h*128 + c] = sum;
    }
    // o_pt inverse transform + norm
    if (t < 96) {   // t = h*8+p
        const float* R = rots  + (size_t)i * 9;
        const float* T = trans + (size_t)i * 3;
        const float r0 = opt_raw[t*3+0] - T[0];
        const float r1 = opt_raw[t*3+1] - T[1];
        const float r2 = opt_raw[t*3+2] - T[2];
        const float o0 = R[0]*r0 + R[3]*r1 + R[6]*r2;
        const float o1 = R[1]*r0 + R[4]*r1 + R[7]*r2;
        const float o2 = R[2]*r0 + R[5]*r1 + R[8]*r2;
        crow[192 +   0 + t] = o0;
        crow[192 +  96 + t] = o1;
        crow[192 + 192 + t] = o2;
        crow[480 + t] = sqrtf(o0*o0 + o1*o1 + o2*o2 + 1e-8f);
    }
}

// ---------------------------------------------------------------------------
// k_outp: split-K partials of cat @ Wout (K=2112=6x352). 256 thr, 2x2 waves.
// ---------------------------------------------------------------------------
__global__ __launch_bounds__(256) void k_outp(
    const float* __restrict__ cat, const float* __restrict__ Wout,
    float* __restrict__ outp)
{
    __shared__ float A[32*36];
    __shared__ float Bt[32*36];
    const int t    = threadIdx.x;
    const int wave = t >> 6, lane = t & 63;
    const int wr   = wave >> 1, wc = wave & 1;
    const int ly   = lane >> 3, lx = lane & 7;
    const int i0 = blockIdx.x * 32, n0 = blockIdx.y * 32;
    const int kq = blockIdx.z;
    const int sr = t >> 3, sk = (t & 7) * 4;

    float acc00=0.f, acc01=0.f, acc10=0.f, acc11=0.f;
    for (int kc = 0; kc < 11; ++kc) {
        const int kb = kq*352 + kc*32;
        __syncthreads();
        *(float4*)&A[sr*36 + sk] = *(const float4*)&cat[(size_t)(i0+sr)*2112 + kb + sk];
        const float4 wv = *(const float4*)&Wout[(size_t)(kb+sr)*384 + n0 + sk];
        Bt[(sk+0)*36 + sr] = wv.x;
        Bt[(sk+1)*36 + sr] = wv.y;
        Bt[(sk+2)*36 + sr] = wv.z;
        Bt[(sk+3)*36 + sr] = wv.w;
        __syncthreads();
        #pragma unroll
        for (int k4 = 0; k4 < 32; k4 += 4) {
            const float4 a0 = *(const float4*)&A [(wr*16 + ly*2 + 0)*36 + k4];
            const float4 a1 = *(const float4*)&A [(wr*16 + ly*2 + 1)*36 + k4];
            const float4 b0 = *(const float4*)&Bt[(wc*16 + lx*2 + 0)*36 + k4];
            const float4 b1 = *(const float4*)&Bt[(wc*16 + lx*2 + 1)*36 + k4];
            acc00 = fmaf(a0.x,b0.x, fmaf(a0.y,b0.y, fmaf(a0.z,b0.z, fmaf(a0.w,b0.w, acc00))));
            acc01 = fmaf(a0.x,b1.x, fmaf(a0.y,b1.y, fmaf(a0.z,b1.z, fmaf(a0.w,b1.w, acc01))));
            acc10 = fmaf(a1.x,b0.x, fmaf(a1.y,b0.y, fmaf(a1.z,b0.z, fmaf(a1.w,b0.w, acc10))));
            acc11 = fmaf(a1.x,b1.x, fmaf(a1.y,b1.y, fmaf(a1.z,b1.z, fmaf(a1.w,b1.w, acc11))));
        }
    }
    float* op = outp + (size_t)kq * 196608;
    const int row = i0 + wr*16 + ly*2, col = n0 + wc*16 + lx*2;
    op[(size_t)(row+0)*384 + col+0] = acc00;
    op[(size_t)(row+0)*384 + col+1] = acc01;
    op[(size_t)(row+1)*384 + col+0] = acc10;
    op[(size_t)(row+1)*384 + col+1] = acc11;
}

__global__ __launch_bounds__(256) void k_red(
    const float* __restrict__ outp, const float* __restrict__ bout,
    float* __restrict__ out)
{
    const int e = blockIdx.x * 256 + threadIdx.x;
    float v = bout[e % 384];
    #pragma unroll
    for (int q = 0; q < 6; ++q) v += outp[(size_t)q*196608 + e];
    out[e] = v;
}

// ---------------------------------------------------------------------------
extern "C" void kernel_launch(void* const* d_in, const int* in_sizes, int n_in,
                              void* d_out, int out_size, void* d_ws, size_t ws_size,
                              hipStream_t stream)
{
    const float* s      = (const float*)d_in[0];
    const float* z      = (const float*)d_in[1];
    const float* rots   = (const float*)d_in[2];
    const float* trans  = (const float*)d_in[3];
    const float* mask   = (const float*)d_in[4];
    const float* Wq     = (const float*)d_in[5];
    const float* bq     = (const float*)d_in[6];
    const float* Wkv    = (const float*)d_in[7];
    const float* bkv    = (const float*)d_in[8];
    const float* Wqp    = (const float*)d_in[9];
    const float* bqp    = (const float*)d_in[10];
    const float* Wkvp   = (const float*)d_in[11];
    const float* bkvp   = (const float*)d_in[12];
    const float* Wb     = (const float*)d_in[13];
    const float* bb     = (const float*)d_in[14];
    const float* head_w = (const float*)d_in[15];
    const float* Wout   = (const float*)d_in[16];
    const float* bout   = (const float*)d_in[17];
    float* out = (float*)d_out;

    float* ws    = (float*)d_ws;
    float* proj  = ws;                      // 589824
    float* qp_g  = proj  + 589824;          // 73728
    float* kpT   = qp_g  + 73728;           // 73728  [h*12+e][512]
    float* vp_g  = kpT   + 73728;           // 147456
    float* kT    = vp_g  + 147456;          // 98304  [h*16+c][512]
    float* abuf  = kT    + 98304;           // 3145728 (raw logits; later outp)
    float* cat   = abuf  + 3145728;         // 1081344
    float* wbt   = cat   + 1081344;         // 1548  WbT[12][128] + hw[12]
    float* outp  = abuf;                    // 1179648 <= 3145728

    k_proj <<<dim3(16, 36), 256, 0, stream>>>(s, Wq, bq, Wkv, bkv, Wqp, bqp,
                                              Wkvp, bkvp, Wb, head_w,
                                              proj, kT, wbt);
    k_rot  <<<512, 192, 0, stream>>>(proj, rots, trans, qp_g, kpT, vp_g);
    k_logit<<<dim3(512, 8), 256, 0, stream>>>(proj, z, mask, wbt, bb,
                                              qp_g, kT, kpT, abuf);
    k_avp  <<<512, 512, 0, stream>>>(abuf, proj, vp_g, z, rots, trans, cat);
    k_outp <<<dim3(16, 12, 6), 256, 0, stream>>>(cat, Wout, outp);
    k_red  <<<768, 256, 0, stream>>>(outp, bout, out);
}

// Round 20
// 142.861 us; speedup vs baseline: 1.0625x; 1.0081x over previous
//
#include <hip/hip_runtime.h>
#include <hip/hip_bf16.h>
#include <math.h>

#define N_RES 512
#define NPROJ 1152
#define LSTR  520

#define SC_QK 0.14433756729740643f   // sqrt(1/48)
#define SC_B  0.57735026918962576f   // sqrt(1/3)
#define SC_HW 0.13608276348795434f   // sqrt(1/54)

typedef __attribute__((ext_vector_type(8))) short short8;
typedef __attribute__((ext_vector_type(4))) float f32x4;

// hardware bf16 conversion (compiler emits v_cvt_pk_bf16_f32 pairs; m240)
static __device__ __forceinline__ short f2bf(float f) {
    return __builtin_bit_cast(short, __float2bfloat16(f));
}

// branchy weight/bias source selectors (block-uniform col ranges in k_proj)
static __device__ __forceinline__ float wsrc(
    const float* __restrict__ Wq,  const float* __restrict__ Wkv,
    const float* __restrict__ Wqp, const float* __restrict__ Wkvp,
    int k, int col)
{
    if (col < 192)      return Wq  [(size_t)k*192 + col];
    else if (col < 576) return Wkv [(size_t)k*384 + col-192];
    else if (col < 720) return Wqp [(size_t)k*144 + col-576];
    else                return Wkvp[(size_t)k*432 + col-720];
}
static __device__ __forceinline__ float bsrc(
    const float* __restrict__ bq,  const float* __restrict__ bkv,
    const float* __restrict__ bqp, const float* __restrict__ bkvp, int col)
{
    if (col < 192)      return bq  [col];
    else if (col < 576) return bkv [col-192];
    else if (col < 720) return bqp [col-576];
    else                return bkvp[col-720];
}

// ---------------------------------------------------------------------------
// k_proj: proj = s @ [Wq|Wkv|Wqp|Wkvp] + bias (+ kT transposed K copy).
// 256 thr, 2x2 wave grid, 2x2 reg tile. Block (0,0) prologue: wbt (WbT) +
// precomputed per-head softplus weights at wbt[1536..1547].
// ---------------------------------------------------------------------------
__global__ __launch_bounds__(256) void k_proj(
    const float* __restrict__ s,
    const float* __restrict__ Wq,  const float* __restrict__ bq,
    const float* __restrict__ Wkv, const float* __restrict__ bkv,
    const float* __restrict__ Wqp, const float* __restrict__ bqp,
    const float* __restrict__ Wkvp,const float* __restrict__ bkvp,
    const float* __restrict__ Wb,  const float* __restrict__ head_w,
    float* __restrict__ proj, float* __restrict__ kT, float* __restrict__ wbt)
{
    __shared__ float A[32*36];
    __shared__ float Bt[32*36];
    const int t    = threadIdx.x;
    const int wave = t >> 6, lane = t & 63;
    const int wr   = wave >> 1, wc = wave & 1;
    const int ly   = lane >> 3, lx = lane & 7;
    const int i0 = blockIdx.x * 32, c0 = blockIdx.y * 32;
    const int sr = t >> 3, sk = (t & 7) * 4;

    if (blockIdx.x == 0 && blockIdx.y == 0) {   // prologue
        for (int idx = t; idx < 1536; idx += 256) {
            const int h = idx >> 7, c = idx & 127;
            wbt[idx] = Wb[c*12 + h];
        }
        if (t < 12)
            wbt[1536 + t] = log1pf(expf(head_w[t])) * SC_HW;
    }

    float acc00=0.f, acc01=0.f, acc10=0.f, acc11=0.f;
    for (int k0 = 0; k0 < 384; k0 += 32) {
        __syncthreads();
        *(float4*)&A[sr*36 + sk] = *(const float4*)&s[(size_t)(i0+sr)*384 + k0 + sk];
        const int col = c0 + sk;
        float4 wv;
        wv.x = wsrc(Wq,Wkv,Wqp,Wkvp, k0+sr, col+0);
        wv.y = wsrc(Wq,Wkv,Wqp,Wkvp, k0+sr, col+1);
        wv.z = wsrc(Wq,Wkv,Wqp,Wkvp, k0+sr, col+2);
        wv.w = wsrc(Wq,Wkv,Wqp,Wkvp, k0+sr, col+3);
        Bt[(sk+0)*36 + sr] = wv.x;
        Bt[(sk+1)*36 + sr] = wv.y;
        Bt[(sk+2)*36 + sr] = wv.z;
        Bt[(sk+3)*36 + sr] = wv.w;
        __syncthreads();
        #pragma unroll
        for (int k4 = 0; k4 < 32; k4 += 4) {
            const float4 a0 = *(const float4*)&A [(wr*16 + ly*2 + 0)*36 + k4];
            const float4 a1 = *(const float4*)&A [(wr*16 + ly*2 + 1)*36 + k4];
            const float4 b0 = *(const float4*)&Bt[(wc*16 + lx*2 + 0)*36 + k4];
            const float4 b1 = *(const float4*)&Bt[(wc*16 + lx*2 + 1)*36 + k4];
            acc00 = fmaf(a0.x,b0.x, fmaf(a0.y,b0.y, fmaf(a0.z,b0.z, fmaf(a0.w,b0.w, acc00))));
            acc01 = fmaf(a0.x,b1.x, fmaf(a0.y,b1.y, fmaf(a0.z,b1.z, fmaf(a0.w,b1.w, acc01))));
            acc10 = fmaf(a1.x,b0.x, fmaf(a1.y,b0.y, fmaf(a1.z,b0.z, fmaf(a1.w,b0.w, acc10))));
            acc11 = fmaf(a1.x,b1.x, fmaf(a1.y,b1.y, fmaf(a1.z,b1.z, fmaf(a1.w,b1.w, acc11))));
        }
    }
    #pragma unroll
    for (int r = 0; r < 2; ++r)
        #pragma unroll
        for (int c = 0; c < 2; ++c) {
            const int row = i0 + wr*16 + ly*2 + r;
            const int col = c0 + wc*16 + lx*2 + c;
            const float v = (r ? (c ? acc11 : acc10) : (c ? acc01 : acc00))
                            + bsrc(bq,bkv,bqp,bkvp, col);
            proj[(size_t)row*NPROJ + col] = v;
            if (col >= 192 && col < 576) {
                const int w = (col - 192) & 31;
                if (w < 16)
                    kT[(size_t)((((col-192) >> 5) << 4) + w)*512 + row] = v;
            }
        }
}

// ---------------------------------------------------------------------------
// k_rot: rotate/translate qp & kvp. kp written TRANSPOSED: kpT[h*12+e][i].
// ---------------------------------------------------------------------------
__global__ __launch_bounds__(192) void k_rot(
    const float* __restrict__ proj, const float* __restrict__ rots,
    const float* __restrict__ trans,
    float* __restrict__ qp_g, float* __restrict__ kpT, float* __restrict__ vp_g)
{
    const int i = blockIdx.x;
    const int t = threadIdx.x;
    const float* R = rots  + (size_t)i * 9;
    const float* T = trans + (size_t)i * 3;
    const float* row = proj + (size_t)i * NPROJ;
    const float r00=R[0],r01=R[1],r02=R[2],r10=R[3],r11=R[4],r12=R[5],r20=R[6],r21=R[7],r22=R[8];
    const float t0=T[0], t1=T[1], t2=T[2];
    if (t < 48) {
        const int p = t;
        const float v0 = row[576 + p], v1 = row[576 + 48 + p], v2 = row[576 + 96 + p];
        float* dst = qp_g + (size_t)i*144 + p*3;
        dst[0] = r00*v0 + r01*v1 + r02*v2 + t0;
        dst[1] = r10*v0 + r11*v1 + r12*v2 + t1;
        dst[2] = r20*v0 + r21*v1 + r22*v2 + t2;
    } else {
        const int p = t - 48;
        const float v0 = row[720 + p], v1 = row[720 + 144 + p], v2 = row[720 + 288 + p];
        const float o0 = r00*v0 + r01*v1 + r02*v2 + t0;
        const float o1 = r10*v0 + r11*v1 + r12*v2 + t1;
        const float o2 = r20*v0 + r21*v1 + r22*v2 + t2;
        const int h = p / 12, pp = p % 12;
        if (pp < 4) {
            const int e = (h*4 + pp)*3;
            kpT[(size_t)(e+0)*512 + i] = o0;
            kpT[(size_t)(e+1)*512 + i] = o1;
            kpT[(size_t)(e+2)*512 + i] = o2;
        } else {
            float* dst = vp_g + (size_t)i*288 + (h*8+(pp-4))*3;
            dst[0]=o0; dst[1]=o1; dst[2]=o2;
        }
    }
}

// ---------------------------------------------------------------------------
// k_logit: bias via MFMA tile + qk + point + mask -> raw logits.
// grid (512 i, 8 jq) x 256 thr; wave wv owns rows [jq*64 + wv*16, +16).
// ---------------------------------------------------------------------------
__global__ __launch_bounds__(256, 4) void k_logit(
    const float* __restrict__ proj, const float* __restrict__ z,
    const float* __restrict__ mask,
    const float* __restrict__ wbt,  const float* __restrict__ bb,
    const float* __restrict__ qp_g, const float* __restrict__ kT,
    const float* __restrict__ kpT,
    float* __restrict__ a)
{
    const int i  = blockIdx.x, jq = blockIdx.y;   // jq 0..7
    const int t  = threadIdx.x;
    const int j0 = jq * 64;

    __shared__ float qlds[336];       // [0,192)=q, [192,336)=qp
    __shared__ float biasr[64 * 13];  // [row][h], pad 13

    for (int idx = t; idx < 336; idx += 256)
        qlds[idx] = (idx < 192) ? proj[(size_t)i*NPROJ + idx]
                                : qp_g[(size_t)i*144 + (idx-192)];

    // ---- phase 1: bias = z @ Wb via one 16-row MFMA tile per wave ----
    const int wv = t >> 6, lane = t & 63;
    const int r16 = lane & 15, g = lane >> 4;

    short8 bf[4];
    #pragma unroll
    for (int ck = 0; ck < 4; ++ck) {
        float w[8];
        if (r16 < 12) {
            const float4 w0 = *(const float4*)&wbt[r16*128 + ck*32 + g*8];
            const float4 w1 = *(const float4*)&wbt[r16*128 + ck*32 + g*8 + 4];
            w[0]=w0.x; w[1]=w0.y; w[2]=w0.z; w[3]=w0.w;
            w[4]=w1.x; w[5]=w1.y; w[6]=w1.z; w[7]=w1.w;
        } else {
            #pragma unroll
            for (int e = 0; e < 8; ++e) w[e] = 0.f;
        }
        #pragma unroll
        for (int e = 0; e < 8; ++e) bf[ck][e] = f2bf(w[e]);
    }

    const float* zrow = z + ((size_t)i*N_RES + j0 + wv*16 + r16)*128 + g*8;
    f32x4 bacc = {0.f, 0.f, 0.f, 0.f};
    #pragma unroll
    for (int ck = 0; ck < 4; ++ck) {
        const float4 z0 = *(const float4*)&zrow[ck*32];
        const float4 z1 = *(const float4*)&zrow[ck*32 + 4];
        short8 af;
        af[0]=f2bf(z0.x); af[1]=f2bf(z0.y); af[2]=f2bf(z0.z); af[3]=f2bf(z0.w);
        af[4]=f2bf(z1.x); af[5]=f2bf(z1.y); af[6]=f2bf(z1.z); af[7]=f2bf(z1.w);
        bacc = __builtin_amdgcn_mfma_f32_16x16x32_bf16(af, bf[ck], bacc, 0, 0, 0);
    }
    if (r16 < 12) {   // C: col h = r16, local row = wv*16 + g*4 + r
        const int jl = wv*16 + g*4;
        biasr[(jl+0)*13 + r16] = bacc[0];
        biasr[(jl+1)*13 + r16] = bacc[1];
        biasr[(jl+2)*13 + r16] = bacc[2];
        biasr[(jl+3)*13 + r16] = bacc[3];
    }
    __syncthreads();

    // ---- phase 3: logits via kT/kpT (coalesced along j) ----
    const int j = t & 63, gj = j0 + j;
    const int hgrp = t >> 6;              // heads hgrp*3..hgrp*3+2
    const float mterm = 100000.0f * (mask[i]*mask[gj] - 1.0f);
    #pragma unroll
    for (int u = 0; u < 3; ++u) {
        const int h = hgrp*3 + u;
        const float hw = wbt[1536 + h];   // precomputed softplus*SC_HW (s_load)
        float qk = 0.f;
        #pragma unroll
        for (int c = 0; c < 16; ++c)
            qk = fmaf(qlds[h*16+c], kT[(size_t)(h*16+c)*512 + gj], qk);
        float s2 = 0.f;
        #pragma unroll
        for (int e = 0; e < 12; ++e) {
            const float d = qlds[192 + h*12 + e] - kpT[(size_t)(h*12+e)*512 + gj];
            s2 = fmaf(d, d, s2);
        }
        a[(size_t)i*6144 + h*512 + gj] =
            fmaf(qk, SC_QK,
            fmaf(biasr[j*13+h] + bb[h], SC_B,
            fmaf(-0.5f*hw, s2, mterm)));
    }
}

// ---------------------------------------------------------------------------
// k_avp: fused softmax + o/o_pt + o_pair. Block = residue i, 512 thr.
// Epilogue also initializes out[i][:] = bout (row-per-block) so k_outp can
// accumulate with atomics and k_red is eliminated.
// ---------------------------------------------------------------------------
__global__ __launch_bounds__(512) void k_avp(
    const float* __restrict__ a, const float* __restrict__ proj,
    const float* __restrict__ vp_g, const float* __restrict__ z,
    const float* __restrict__ rots, const float* __restrict__ trans,
    const float* __restrict__ bout,
    float* __restrict__ cat, float* __restrict__ out)
{
    const int i = blockIdx.x;
    const int t = threadIdx.x;
    __shared__ float al[12*LSTR];        // 24.96 KB
    __shared__ float opt_raw[288];
    __shared__ float plds[4*12*128];     // 24 KB o_pair partials

    #pragma unroll
    for (int p = 0; p < 3; ++p) {
        const int el = (p*512 + t) * 4;
        const int h = el >> 9, jj = el & 511;
        *(float4*)&al[h*LSTR + jj] = *(const float4*)&a[(size_t)i*6144 + el];
    }
    if (t < 384)   // init out row for k_outp's atomic accumulation
        out[(size_t)i*384 + t] = bout[t];
    __syncthreads();

    // ---- softmax in LDS: wave wv handles rows wv, wv+8 ----
    const int wv = t >> 6, lane = t & 63;
    for (int row = wv; row < 12; row += 8) {
        float e[8];
        float m = -3.4e38f;
        #pragma unroll
        for (int u = 0; u < 8; ++u) { e[u] = al[row*LSTR + lane + u*64]; m = fmaxf(m, e[u]); }
        #pragma unroll
        for (int d = 1; d < 64; d <<= 1) m = fmaxf(m, __shfl_xor(m, d, 64));
        float ssum = 0.f;
        #pragma unroll
        for (int u = 0; u < 8; ++u) { e[u] = expf(e[u] - m); ssum += e[u]; }
        #pragma unroll
        for (int d = 1; d < 64; d <<= 1) ssum += __shfl_xor(ssum, d, 64);
        const float inv = 1.f / ssum;
        #pragma unroll
        for (int u = 0; u < 8; ++u) al[row*LSTR + lane + u*64] = e[u] * inv;
    }
    __syncthreads();

    // ---- o / o_pt phase ----
    float acc0 = 0.f;
    if (t < 480) {
        const int hh    = (t < 192) ? (t >> 4) : (t - 192) / 24;
        const int o_off = 192 + (t >> 4)*32 + 16 + (t & 15);
        const int vi    = t - 192;
        const float* al0 = al + hh*LSTR;
        for (int j0 = 0; j0 < N_RES; j0 += 8) {
            const float4 a00 = *(const float4*)&al0[j0];
            const float4 a01 = *(const float4*)&al0[j0+4];
            float v[8];
            if (t < 192) {
                #pragma unroll
                for (int w = 0; w < 8; ++w) v[w] = proj[(size_t)(j0+w)*NPROJ + o_off];
            } else {
                #pragma unroll
                for (int w = 0; w < 8; ++w) v[w] = vp_g[(size_t)(j0+w)*288 + vi];
            }
            acc0 = fmaf(a00.x,v[0], fmaf(a00.y,v[1], fmaf(a00.z,v[2], fmaf(a00.w,v[3], acc0))));
            acc0 = fmaf(a01.x,v[4], fmaf(a01.y,v[5], fmaf(a01.z,v[6], fmaf(a01.w,v[7], acc0))));
        }
        if (t < 192) cat[(size_t)i*2112 + t] = acc0;
        else         opt_raw[t - 192] = acc0;
    }

    // ---- o_pair phase: c = t&127, j-quarter = t>>7, all 12 heads ----
    {
        const int c = t & 127, jq = t >> 7;
        const float* zb = z + (size_t)i*65536 + (size_t)jq*128*128 + c;
        float accp[12] = {0,0,0,0,0,0,0,0,0,0,0,0};
        for (int j4 = 0; j4 < 128; j4 += 4) {
            const float z0 = zb[(size_t)(j4+0)*128];
            const float z1 = zb[(size_t)(j4+1)*128];
            const float z2 = zb[(size_t)(j4+2)*128];
            const float z3 = zb[(size_t)(j4+3)*128];
            #pragma unroll
            for (int h = 0; h < 12; ++h) {
                const float4 a4 = *(const float4*)&al[h*LSTR + jq*128 + j4];
                accp[h] = fmaf(a4.x, z0, fmaf(a4.y, z1,
                          fmaf(a4.z, z2, fmaf(a4.w, z3, accp[h]))));
            }
        }
        #pragma unroll
        for (int h = 0; h < 12; ++h)
            plds[(jq*12 + h)*128 + c] = accp[h];
    }
    __syncthreads();

    float* crow = cat + (size_t)i * 2112;
    // o_pair reduce: 1536 outputs, 3 per thread
    #pragma unroll
    for (int e = 0; e < 3; ++e) {
        const int o = t + e*512;
        const int h = o >> 7, c = o & 127;
        const float sum = plds[(0*12+h)*128 + c] + plds[(1*12+h)*128 + c]
                        + plds[(2*12+h)*128 + c] + plds[(3*12+h)*128 + c];
        crow[576 + h*128 + c] = sum;
    }
    // o_pt inverse transform + norm
    if (t < 96) {   // t = h*8+p
        const float* R = rots  + (size_t)i * 9;
        const float* T = trans + (size_t)i * 3;
        const float r0 = opt_raw[t*3+0] - T[0];
        const float r1 = opt_raw[t*3+1] - T[1];
        const float r2 = opt_raw[t*3+2] - T[2];
        const float o0 = R[0]*r0 + R[3]*r1 + R[6]*r2;
        const float o1 = R[1]*r0 + R[4]*r1 + R[7]*r2;
        const float o2 = R[2]*r0 + R[5]*r1 + R[8]*r2;
        crow[192 +   0 + t] = o0;
        crow[192 +  96 + t] = o1;
        crow[192 + 192 + t] = o2;
        crow[480 + t] = sqrtf(o0*o0 + o1*o1 + o2*o2 + 1e-8f);
    }
}

// ---------------------------------------------------------------------------
// k_outp: split-K cat @ Wout (K=2112=6x352), accumulated into out via
// device-scope atomicAdd (out pre-initialized with bout by k_avp).
// ---------------------------------------------------------------------------
__global__ __launch_bounds__(256) void k_outp(
    const float* __restrict__ cat, const float* __restrict__ Wout,
    float* __restrict__ out)
{
    __shared__ float A[32*36];
    __shared__ float Bt[32*36];
    const int t    = threadIdx.x;
    const int wave = t >> 6, lane = t & 63;
    const int wr   = wave >> 1, wc = wave & 1;
    const int ly   = lane >> 3, lx = lane & 7;
    const int i0 = blockIdx.x * 32, n0 = blockIdx.y * 32;
    const int kq = blockIdx.z;
    const int sr = t >> 3, sk = (t & 7) * 4;

    float acc00=0.f, acc01=0.f, acc10=0.f, acc11=0.f;
    for (int kc = 0; kc < 11; ++kc) {
        const int kb = kq*352 + kc*32;
        __syncthreads();
        *(float4*)&A[sr*36 + sk] = *(const float4*)&cat[(size_t)(i0+sr)*2112 + kb + sk];
        const float4 wv = *(const float4*)&Wout[(size_t)(kb+sr)*384 + n0 + sk];
        Bt[(sk+0)*36 + sr] = wv.x;
        Bt[(sk+1)*36 + sr] = wv.y;
        Bt[(sk+2)*36 + sr] = wv.z;
        Bt[(sk+3)*36 + sr] = wv.w;
        __syncthreads();
        #pragma unroll
        for (int k4 = 0; k4 < 32; k4 += 4) {
            const float4 a0 = *(const float4*)&A [(wr*16 + ly*2 + 0)*36 + k4];
            const float4 a1 = *(const float4*)&A [(wr*16 + ly*2 + 1)*36 + k4];
            const float4 b0 = *(const float4*)&Bt[(wc*16 + lx*2 + 0)*36 + k4];
            const float4 b1 = *(const float4*)&Bt[(wc*16 + lx*2 + 1)*36 + k4];
            acc00 = fmaf(a0.x,b0.x, fmaf(a0.y,b0.y, fmaf(a0.z,b0.z, fmaf(a0.w,b0.w, acc00))));
            acc01 = fmaf(a0.x,b1.x, fmaf(a0.y,b1.y, fmaf(a0.z,b1.z, fmaf(a0.w,b1.w, acc01))));
            acc10 = fmaf(a1.x,b0.x, fmaf(a1.y,b0.y, fmaf(a1.z,b0.z, fmaf(a1.w,b0.w, acc10))));
            acc11 = fmaf(a1.x,b1.x, fmaf(a1.y,b1.y, fmaf(a1.z,b1.z, fmaf(a1.w,b1.w, acc11))));
        }
    }
    const int row = i0 + wr*16 + ly*2, col = n0 + wc*16 + lx*2;
    atomicAdd(&out[(size_t)(row+0)*384 + col+0], acc00);
    atomicAdd(&out[(size_t)(row+0)*384 + col+1], acc01);
    atomicAdd(&out[(size_t)(row+1)*384 + col+0], acc10);
    atomicAdd(&out[(size_t)(row+1)*384 + col+1], acc11);
}

// ---------------------------------------------------------------------------
extern "C" void kernel_launch(void* const* d_in, const int* in_sizes, int n_in,
                              void* d_out, int out_size, void* d_ws, size_t ws_size,
                              hipStream_t stream)
{
    const float* s      = (const float*)d_in[0];
    const float* z      = (const float*)d_in[1];
    const float* rots   = (const float*)d_in[2];
    const float* trans  = (const float*)d_in[3];
    const float* mask   = (const float*)d_in[4];
    const float* Wq     = (const float*)d_in[5];
    const float* bq     = (const float*)d_in[6];
    const float* Wkv    = (const float*)d_in[7];
    const float* bkv    = (const float*)d_in[8];
    const float* Wqp    = (const float*)d_in[9];
    const float* bqp    = (const float*)d_in[10];
    const float* Wkvp   = (const float*)d_in[11];
    const float* bkvp   = (const float*)d_in[12];
    const float* Wb     = (const float*)d_in[13];
    const float* bb     = (const float*)d_in[14];
    const float* head_w = (const float*)d_in[15];
    const float* Wout   = (const float*)d_in[16];
    const float* bout   = (const float*)d_in[17];
    float* out = (float*)d_out;

    float* ws    = (float*)d_ws;
    float* proj  = ws;                      // 589824
    float* qp_g  = proj  + 589824;          // 73728
    float* kpT   = qp_g  + 73728;           // 73728  [h*12+e][512]
    float* vp_g  = kpT   + 73728;           // 147456
    float* kT    = vp_g  + 147456;          // 98304  [h*16+c][512]
    float* abuf  = kT    + 98304;           // 3145728 (raw logits)
    float* cat   = abuf  + 3145728;         // 1081344
    float* wbt   = cat   + 1081344;         // 1548  WbT[12][128] + hw[12]

    k_proj <<<dim3(16, 36), 256, 0, stream>>>(s, Wq, bq, Wkv, bkv, Wqp, bqp,
                                              Wkvp, bkvp, Wb, head_w,
                                              proj, kT, wbt);
    k_rot  <<<512, 192, 0, stream>>>(proj, rots, trans, qp_g, kpT, vp_g);
    k_logit<<<dim3(512, 8), 256, 0, stream>>>(proj, z, mask, wbt, bb,
                                              qp_g, kT, kpT, abuf);
    k_avp  <<<512, 512, 0, stream>>>(abuf, proj, vp_g, z, rots, trans, bout,
                                     cat, out);
    k_outp <<<dim3(16, 12, 6), 256, 0, stream>>>(cat, Wout, out);
}